// Round 12
// baseline (170.913 us; speedup 1.0000x reference)
//
#include <hip/hip_runtime.h>
#include <cstdint>
#include <cstddef>

// ContrastiveLoss: B=8192, D=256 fp32 inputs.
// loss = mean_b [ log( exp(2*pos_b) + sum_c exp(2*z_i[b].z_k[c]) ) - 2*pos_b ]
// R11: R10's barrier-free fragment-packed GEMM, widened to 8-wave blocks so
// LDS/wave halves -> 16 waves/CU (4 waves/SIMD) for latency hiding.
//   block tile: 128 rows x (NT=4 x 256) cols; waves 2M x 4N, wave tile 64x64.
//   A panel (64 packed frags, 64 KB) staged to LDS once; ONE barrier; then
//   free-run: per step 4 ds_read_b128 (A) + 4 global dwordx4 (B, packed,
//   dbuf 2 steps ahead) + 16 MFMA. No barriers in the loop.
// exp fused per col-tile; shuffle-reduce + atomics once per block.

constexpr int   D_DIM = 256;
constexpr float INV_T = 2.0f;   // 1/T, T=0.5

constexpr int BM = 128;         // block rows
constexpr int NT = 4;           // col-tiles per block (each 256 cols)

typedef __attribute__((ext_vector_type(8))) short  bf16x8;
typedef __attribute__((ext_vector_type(4))) float  f32x4;

__device__ __forceinline__ unsigned short f32_to_bf16(float f) {
    unsigned int u = __float_as_uint(f);
    u += 0x7FFFu + ((u >> 16) & 1u);          // RNE
    return (unsigned short)(u >> 16);
}

__device__ __forceinline__ void gload_lds16(const void* g, void* l) {
    auto gp = reinterpret_cast<const __attribute__((address_space(1))) unsigned int*>(
        reinterpret_cast<uintptr_t>(g));
    auto lp = reinterpret_cast<__attribute__((address_space(3))) unsigned int*>(
        reinterpret_cast<uintptr_t>(l));
    __builtin_amdgcn_global_load_lds(gp, lp, 16, 0, 0);
}

// ---------------------------------------------------------------------------
// Kernel 1: per-16-row group: norms, pos_logit, rowsum init, PACKED bf16 out.
// Thread t: row_local = t>>4, chunk c = t&15 (16 elems). (verified R8/R10)
// Packed layout: frag (g,kt) = 1 KB contiguous; lane l owns bytes [l*16,+16)
//   (row = g*16 + (l&15), k = kt*32 + (l>>4)*8).
// ---------------------------------------------------------------------------
__global__ __launch_bounds__(256) void prep_kernel(
    const float* __restrict__ ei, const float* __restrict__ ej,
    const float* __restrict__ ek,
    unsigned short* __restrict__ zip, unsigned short* __restrict__ zkp,
    float* __restrict__ pos_logit, float* __restrict__ rowsum)
{
    const int t  = (int)threadIdx.x;
    const int rl = t >> 4;              // row within group (0..15)
    const int c  = t & 15;              // 16-elem chunk (0..15)
    const int g  = (int)blockIdx.x;     // row group
    const int row = g * 16 + rl;

    const float4* pi = (const float4*)(ei + (size_t)row * D_DIM + c * 16);
    const float4* pj = (const float4*)(ej + (size_t)row * D_DIM + c * 16);
    const float4* pk = (const float4*)(ek + (size_t)row * D_DIM + c * 16);
    float4 vi[4], vj[4], vk[4];
    #pragma unroll
    for (int q = 0; q < 4; ++q) { vi[q] = pi[q]; vj[q] = pj[q]; vk[q] = pk[q]; }

    float ssi = 0.f, ssj = 0.f, ssk = 0.f, dij = 0.f;
    #pragma unroll
    for (int q = 0; q < 4; ++q) {
        ssi += vi[q].x*vi[q].x + vi[q].y*vi[q].y + vi[q].z*vi[q].z + vi[q].w*vi[q].w;
        ssj += vj[q].x*vj[q].x + vj[q].y*vj[q].y + vj[q].z*vj[q].z + vj[q].w*vj[q].w;
        ssk += vk[q].x*vk[q].x + vk[q].y*vk[q].y + vk[q].z*vk[q].z + vk[q].w*vk[q].w;
        dij += vi[q].x*vj[q].x + vi[q].y*vj[q].y + vi[q].z*vj[q].z + vi[q].w*vj[q].w;
    }
    #pragma unroll
    for (int off = 1; off <= 8; off <<= 1) {    // reduce over the 16 c-lanes
        ssi += __shfl_xor(ssi, off);
        ssj += __shfl_xor(ssj, off);
        ssk += __shfl_xor(ssk, off);
        dij += __shfl_xor(dij, off);
    }
    const float ri = INV_T / fmaxf(sqrtf(ssi), 1e-12f);   // fold 1/T into z_i
    const float rj = 1.0f  / fmaxf(sqrtf(ssj), 1e-12f);
    const float rk = 1.0f  / fmaxf(sqrtf(ssk), 1e-12f);

    bf16x8 hi0, hi1, hk0, hk1;
    #pragma unroll
    for (int q = 0; q < 4; ++q) {
        const float* fi = &vi[q].x;
        const float* fk = &vk[q].x;
        #pragma unroll
        for (int e = 0; e < 4; ++e) {
            const int idx = q * 4 + e;          // 0..15
            const unsigned short bi = f32_to_bf16(fi[e] * ri);
            const unsigned short bk = f32_to_bf16(fk[e] * rk);
            if (idx < 8) { hi0[idx] = (short)bi; hk0[idx] = (short)bk; }
            else         { hi1[idx - 8] = (short)bi; hk1[idx - 8] = (short)bk; }
        }
    }
    const int kt    = c >> 1;
    const int lane0 = rl + 16 * ((c & 1) * 2);
    const size_t fb = ((size_t)g * 8 + kt) * 512;    // frag base (elems)
    *(bf16x8*)(zip + fb + (size_t)lane0 * 8)        = hi0;
    *(bf16x8*)(zip + fb + (size_t)(lane0 + 16) * 8) = hi1;
    *(bf16x8*)(zkp + fb + (size_t)lane0 * 8)        = hk0;
    *(bf16x8*)(zkp + fb + (size_t)(lane0 + 16) * 8) = hk1;

    if (c == 0) {
        pos_logit[row] = dij * ri * rj;   // ri already includes 1/T
        rowsum[row]    = 0.0f;
    }
}

// ---------------------------------------------------------------------------
// Kernel 2: rows [by*128,+128) x cols [bx*1024,+1024) of exp-sum of
// (2*Z_i).Z_k^T. 8 waves (wr = w>>2 in {0,1}, wc = w&3 in {0..3}),
// wave tile 64x64 = 4x4 frags of 16x16x32. A panel (64 frags, 64 KB
// contiguous) staged to LDS once (8 linear gload_lds per wave), one barrier,
// then free-run: 4 ds_read_b128 (A) + 4 global dwordx4 (B), dbuf 2 steps;
// 16 MFMA per step; NO barriers in the loop.
// ---------------------------------------------------------------------------
__global__ __launch_bounds__(512, 4) void sim_mfma_kernel(
    const unsigned short* __restrict__ zip, const unsigned short* __restrict__ zkp,
    float* __restrict__ rowsum)
{
    __shared__ unsigned short Alds[64][512];   // 64 frags x 1 KB = 64 KB

    const int t  = (int)threadIdx.x;
    const int w  = t >> 6;        // wave 0..7
    const int l  = t & 63;
    const int wr = w >> 2;        // row half (0..1)
    const int wc = w & 3;         // col quarter (0..3)
    const int rowBase = (int)blockIdx.y * BM;

    // ---- prologue: stage A panel (contiguous 64 KB in packed layout) ----
    // frag indices [by*64, +64); wave w stages frags [w*8, +8).
    const unsigned short* Apanel = zip + ((size_t)blockIdx.y * 64) * 512;
    #pragma unroll
    for (int f = 0; f < 8; ++f)
        gload_lds16(Apanel + (((size_t)(w * 8 + f)) << 9) + (size_t)l * 8,
                    &Alds[w * 8 + f][0]);
    asm volatile("s_waitcnt vmcnt(0)" ::: "memory");
    __builtin_amdgcn_s_barrier();      // the ONLY barrier

    // ---- A frag read (LDS): frag (mi,kt) at Alds[(wr*4+mi)*8 + kt], +l*8
    #define LDA(dst, s_) {                                                    \
        const int kt_ = (s_) & 7;                                             \
        _Pragma("unroll")                                                     \
        for (int mi = 0; mi < 4; ++mi)                                        \
            dst[mi] = *(const bf16x8*)&Alds[(wr * 4 + mi) * 8 + kt_][l * 8];  \
    }
    // ---- B frag read (global, packed): group = bx*64 + wc*4 + nt*16 + ni;
    // frag (nt,ni,kt) at Bbase + (((nt*16 + ni)*8 + kt) << 9)
    const unsigned short* Bbase =
        zkp + (((size_t)blockIdx.x * 64 + wc * 4) * 8) * 512 + (size_t)l * 8;
    #define LDB(dst, s_) {                                                    \
        const int nt_ = (s_) >> 3, kt_ = (s_) & 7;                            \
        _Pragma("unroll")                                                     \
        for (int ni = 0; ni < 4; ++ni)                                        \
            dst[ni] = *(const bf16x8*)(Bbase + (((nt_ * 16 + ni) * 8 + kt_) << 9)); \
    }

    bf16x8 aX[4], aY[4], bX[4], bY[4];
    LDA(aX, 0); LDB(bX, 0);           // step 0 -> X
    LDA(aY, 1); LDB(bY, 1);           // step 1 -> Y

    float partAcc[4][4] = {};

    for (int nt = 0; nt < NT; ++nt) {
        f32x4 acc[4][4] = {};

        #pragma unroll
        for (int kt = 0; kt < 8; ++kt) {
            const int s  = nt * 8 + kt;
            const int s2 = (s + 2 > NT * 8 - 1) ? (NT * 8 - 1) : (s + 2);

            if ((kt & 1) == 0) {
                __builtin_amdgcn_s_setprio(1);
                #pragma unroll
                for (int mi = 0; mi < 4; ++mi)
                    #pragma unroll
                    for (int ni = 0; ni < 4; ++ni)
                        acc[mi][ni] = __builtin_amdgcn_mfma_f32_16x16x32_bf16(
                            aX[mi], bX[ni], acc[mi][ni], 0, 0, 0);
                __builtin_amdgcn_s_setprio(0);
                LDA(aX, s2); LDB(bX, s2);          // refill X for step s+2
            } else {
                __builtin_amdgcn_s_setprio(1);
                #pragma unroll
                for (int mi = 0; mi < 4; ++mi)
                    #pragma unroll
                    for (int ni = 0; ni < 4; ++ni)
                        acc[mi][ni] = __builtin_amdgcn_mfma_f32_16x16x32_bf16(
                            aY[mi], bY[ni], acc[mi][ni], 0, 0, 0);
                __builtin_amdgcn_s_setprio(0);
                LDA(aY, s2); LDB(bY, s2);          // refill Y for step s+2
            }
        }

        // per-tile epilogue: exp + in-lane partial sums (A pre-scaled by 2)
        #pragma unroll
        for (int mi = 0; mi < 4; ++mi)
            #pragma unroll
            for (int r = 0; r < 4; ++r) {
                float s = 0.f;
                #pragma unroll
                for (int ni = 0; ni < 4; ++ni)
                    s += __expf(acc[mi][ni][r]);
                partAcc[mi][r] += s;
            }
    }
    #undef LDA
    #undef LDB

    // block epilogue: reduce across the 16 column-lanes, one atomic set
    #pragma unroll
    for (int off = 1; off <= 8; off <<= 1)
        #pragma unroll
        for (int mi = 0; mi < 4; ++mi)
            #pragma unroll
            for (int r = 0; r < 4; ++r)
                partAcc[mi][r] += __shfl_xor(partAcc[mi][r], off);

    if ((l & 15) == 0) {
        const int rg = (l >> 4) * 4;     // C/D layout: row = (l>>4)*4 + reg
        #pragma unroll
        for (int mi = 0; mi < 4; ++mi)
            #pragma unroll
            for (int r = 0; r < 4; ++r)
                atomicAdd(&rowsum[rowBase + wr * 64 + mi * 16 + rg + r],
                          partAcc[mi][r]);
    }
}

// ---------------------------------------------------------------------------
// Kernel 3: loss = mean_b [ log(exp(pos_b) + rowsum_b) - pos_b ]
// ---------------------------------------------------------------------------
__global__ __launch_bounds__(1024) void finalize_kernel(
    const float* __restrict__ pos_logit, const float* __restrict__ rowsum,
    float* __restrict__ out, int B)
{
    __shared__ float red[1024];
    float acc = 0.f;
    for (int b = (int)threadIdx.x; b < B; b += 1024) {
        const float pl = pos_logit[b];
        acc += logf(expf(pl) + rowsum[b]) - pl;
    }
    red[threadIdx.x] = acc;
    __syncthreads();
    #pragma unroll
    for (int s = 512; s; s >>= 1) {
        if ((int)threadIdx.x < s) red[threadIdx.x] += red[threadIdx.x + s];
        __syncthreads();
    }
    if (threadIdx.x == 0) out[0] = red[0] / (float)B;
}

// ---------------------------------------------------------------------------
extern "C" void kernel_launch(void* const* d_in, const int* in_sizes, int n_in,
                              void* d_out, int out_size, void* d_ws, size_t ws_size,
                              hipStream_t stream)
{
    const float* ei = (const float*)d_in[0];
    const float* ej = (const float*)d_in[1];
    const float* ek = (const float*)d_in[2];
    const int B = in_sizes[0] / D_DIM;   // 8192

    unsigned short* zip = (unsigned short*)d_ws;            // 4 MB packed A
    unsigned short* zkp = zip + (size_t)B * D_DIM;          // 4 MB packed B
    float* rowsum       = (float*)(zkp + (size_t)B * D_DIM);
    float* pos_logit    = rowsum + B;

    prep_kernel<<<dim3(B / 16), dim3(256), 0, stream>>>(
        ei, ej, ek, zip, zkp, pos_logit, rowsum);

    dim3 grid(B / (NT * 256), B / BM);   // (8, 64) = 512 blocks x 512 thr
    sim_mfma_kernel<<<grid, dim3(512), 0, stream>>>(zip, zkp, rowsum);

    finalize_kernel<<<dim3(1), dim3(1024), 0, stream>>>(
        pos_logit, rowsum, (float*)d_out, B);
}

// Round 13
// 55.800 us; speedup vs baseline: 3.0629x; 3.0629x over previous
//
#include <hip/hip_runtime.h>
#include <cstdint>
#include <cstddef>

// ContrastiveLoss: B=8192, D=256 fp32 inputs.
// loss = mean_b [ log( exp(2*pos_b) + sum_c exp(2*z_i[b].z_k[c]) ) - 2*pos_b ]
// R12: R11 with the register cap fixed: __launch_bounds__(512, 2) so the
// compiler allocates its natural ~128 VGPR (no spill). 8-wave blocks,
// A panel in LDS (64 KB/block -> 2 blocks/CU = 4 waves/SIMD), barrier-free
// free-running loop over fragment-packed operands.
//   block tile: 128 rows x (NT=4 x 256) cols; waves 2M x 4N, wave tile 64x64.
//   per step: 4 ds_read_b128 (A) + 4 global dwordx4 (B, dbuf 2 ahead) +
//   16 MFMA; no barriers in the loop.
// exp fused per col-tile; shuffle-reduce + atomics once per block.

constexpr int   D_DIM = 256;
constexpr float INV_T = 2.0f;   // 1/T, T=0.5

constexpr int BM = 128;         // block rows
constexpr int NT = 4;           // col-tiles per block (each 256 cols)

typedef __attribute__((ext_vector_type(8))) short  bf16x8;
typedef __attribute__((ext_vector_type(4))) float  f32x4;

__device__ __forceinline__ unsigned short f32_to_bf16(float f) {
    unsigned int u = __float_as_uint(f);
    u += 0x7FFFu + ((u >> 16) & 1u);          // RNE
    return (unsigned short)(u >> 16);
}

__device__ __forceinline__ void gload_lds16(const void* g, void* l) {
    auto gp = reinterpret_cast<const __attribute__((address_space(1))) unsigned int*>(
        reinterpret_cast<uintptr_t>(g));
    auto lp = reinterpret_cast<__attribute__((address_space(3))) unsigned int*>(
        reinterpret_cast<uintptr_t>(l));
    __builtin_amdgcn_global_load_lds(gp, lp, 16, 0, 0);
}

// ---------------------------------------------------------------------------
// Kernel 1: per-16-row group: norms, pos_logit, rowsum init, PACKED bf16 out.
// Thread t: row_local = t>>4, chunk c = t&15 (16 elems). (verified R8/R10)
// Packed layout: frag (g,kt) = 1 KB contiguous; lane l owns bytes [l*16,+16)
//   (row = g*16 + (l&15), k = kt*32 + (l>>4)*8).
// ---------------------------------------------------------------------------
__global__ __launch_bounds__(256) void prep_kernel(
    const float* __restrict__ ei, const float* __restrict__ ej,
    const float* __restrict__ ek,
    unsigned short* __restrict__ zip, unsigned short* __restrict__ zkp,
    float* __restrict__ pos_logit, float* __restrict__ rowsum)
{
    const int t  = (int)threadIdx.x;
    const int rl = t >> 4;              // row within group (0..15)
    const int c  = t & 15;              // 16-elem chunk (0..15)
    const int g  = (int)blockIdx.x;     // row group
    const int row = g * 16 + rl;

    const float4* pi = (const float4*)(ei + (size_t)row * D_DIM + c * 16);
    const float4* pj = (const float4*)(ej + (size_t)row * D_DIM + c * 16);
    const float4* pk = (const float4*)(ek + (size_t)row * D_DIM + c * 16);
    float4 vi[4], vj[4], vk[4];
    #pragma unroll
    for (int q = 0; q < 4; ++q) { vi[q] = pi[q]; vj[q] = pj[q]; vk[q] = pk[q]; }

    float ssi = 0.f, ssj = 0.f, ssk = 0.f, dij = 0.f;
    #pragma unroll
    for (int q = 0; q < 4; ++q) {
        ssi += vi[q].x*vi[q].x + vi[q].y*vi[q].y + vi[q].z*vi[q].z + vi[q].w*vi[q].w;
        ssj += vj[q].x*vj[q].x + vj[q].y*vj[q].y + vj[q].z*vj[q].z + vj[q].w*vj[q].w;
        ssk += vk[q].x*vk[q].x + vk[q].y*vk[q].y + vk[q].z*vk[q].z + vk[q].w*vk[q].w;
        dij += vi[q].x*vj[q].x + vi[q].y*vj[q].y + vi[q].z*vj[q].z + vi[q].w*vj[q].w;
    }
    #pragma unroll
    for (int off = 1; off <= 8; off <<= 1) {    // reduce over the 16 c-lanes
        ssi += __shfl_xor(ssi, off);
        ssj += __shfl_xor(ssj, off);
        ssk += __shfl_xor(ssk, off);
        dij += __shfl_xor(dij, off);
    }
    const float ri = INV_T / fmaxf(sqrtf(ssi), 1e-12f);   // fold 1/T into z_i
    const float rj = 1.0f  / fmaxf(sqrtf(ssj), 1e-12f);
    const float rk = 1.0f  / fmaxf(sqrtf(ssk), 1e-12f);

    bf16x8 hi0, hi1, hk0, hk1;
    #pragma unroll
    for (int q = 0; q < 4; ++q) {
        const float* fi = &vi[q].x;
        const float* fk = &vk[q].x;
        #pragma unroll
        for (int e = 0; e < 4; ++e) {
            const int idx = q * 4 + e;          // 0..15
            const unsigned short bi = f32_to_bf16(fi[e] * ri);
            const unsigned short bk = f32_to_bf16(fk[e] * rk);
            if (idx < 8) { hi0[idx] = (short)bi; hk0[idx] = (short)bk; }
            else         { hi1[idx - 8] = (short)bi; hk1[idx - 8] = (short)bk; }
        }
    }
    const int kt    = c >> 1;
    const int lane0 = rl + 16 * ((c & 1) * 2);
    const size_t fb = ((size_t)g * 8 + kt) * 512;    // frag base (elems)
    *(bf16x8*)(zip + fb + (size_t)lane0 * 8)        = hi0;
    *(bf16x8*)(zip + fb + (size_t)(lane0 + 16) * 8) = hi1;
    *(bf16x8*)(zkp + fb + (size_t)lane0 * 8)        = hk0;
    *(bf16x8*)(zkp + fb + (size_t)(lane0 + 16) * 8) = hk1;

    if (c == 0) {
        pos_logit[row] = dij * ri * rj;   // ri already includes 1/T
        rowsum[row]    = 0.0f;
    }
}

// ---------------------------------------------------------------------------
// Kernel 2: rows [by*128,+128) x cols [bx*1024,+1024) of exp-sum of
// (2*Z_i).Z_k^T. 8 waves (wr = w>>2 in {0,1}, wc = w&3 in {0..3}),
// wave tile 64x64 = 4x4 frags of 16x16x32. A panel (64 frags, 64 KB
// contiguous) staged to LDS once (8 linear gload_lds per wave), one barrier,
// then free-run: 4 ds_read_b128 (A) + 4 global dwordx4 (B), dbuf 2 steps;
// 16 MFMA per step; NO barriers in the loop.
// ---------------------------------------------------------------------------
__global__ __launch_bounds__(512, 2) void sim_mfma_kernel(
    const unsigned short* __restrict__ zip, const unsigned short* __restrict__ zkp,
    float* __restrict__ rowsum)
{
    __shared__ unsigned short Alds[64][512];   // 64 frags x 1 KB = 64 KB

    const int t  = (int)threadIdx.x;
    const int w  = t >> 6;        // wave 0..7
    const int l  = t & 63;
    const int wr = w >> 2;        // row half (0..1)
    const int wc = w & 3;         // col quarter (0..3)
    const int rowBase = (int)blockIdx.y * BM;

    // ---- prologue: stage A panel (contiguous 64 KB in packed layout) ----
    // frag indices [by*64, +64); wave w stages frags [w*8, +8).
    const unsigned short* Apanel = zip + ((size_t)blockIdx.y * 64) * 512;
    #pragma unroll
    for (int f = 0; f < 8; ++f)
        gload_lds16(Apanel + (((size_t)(w * 8 + f)) << 9) + (size_t)l * 8,
                    &Alds[w * 8 + f][0]);
    asm volatile("s_waitcnt vmcnt(0)" ::: "memory");
    __builtin_amdgcn_s_barrier();      // the ONLY barrier

    // ---- A frag read (LDS): frag (mi,kt) at Alds[(wr*4+mi)*8 + kt], +l*8
    #define LDA(dst, s_) {                                                    \
        const int kt_ = (s_) & 7;                                             \
        _Pragma("unroll")                                                     \
        for (int mi = 0; mi < 4; ++mi)                                        \
            dst[mi] = *(const bf16x8*)&Alds[(wr * 4 + mi) * 8 + kt_][l * 8];  \
    }
    // ---- B frag read (global, packed): group = bx*64 + nt*16 + wc*4 + ni;
    // frag at Bbase + (((nt*16 + ni)*8 + kt) << 9)
    const unsigned short* Bbase =
        zkp + (((size_t)blockIdx.x * 64 + wc * 4) * 8) * 512 + (size_t)l * 8;
    #define LDB(dst, s_) {                                                    \
        const int nt_ = (s_) >> 3, kt_ = (s_) & 7;                            \
        _Pragma("unroll")                                                     \
        for (int ni = 0; ni < 4; ++ni)                                        \
            dst[ni] = *(const bf16x8*)(Bbase + (((nt_ * 16 + ni) * 8 + kt_) << 9)); \
    }

    bf16x8 aX[4], aY[4], bX[4], bY[4];
    LDA(aX, 0); LDB(bX, 0);           // step 0 -> X
    LDA(aY, 1); LDB(bY, 1);           // step 1 -> Y

    float partAcc[4][4] = {};

    for (int nt = 0; nt < NT; ++nt) {
        f32x4 acc[4][4] = {};

        #pragma unroll
        for (int kt = 0; kt < 8; ++kt) {
            const int s  = nt * 8 + kt;
            const int s2 = (s + 2 > NT * 8 - 1) ? (NT * 8 - 1) : (s + 2);

            if ((kt & 1) == 0) {
                __builtin_amdgcn_s_setprio(1);
                #pragma unroll
                for (int mi = 0; mi < 4; ++mi)
                    #pragma unroll
                    for (int ni = 0; ni < 4; ++ni)
                        acc[mi][ni] = __builtin_amdgcn_mfma_f32_16x16x32_bf16(
                            aX[mi], bX[ni], acc[mi][ni], 0, 0, 0);
                __builtin_amdgcn_s_setprio(0);
                LDA(aX, s2); LDB(bX, s2);          // refill X for step s+2
            } else {
                __builtin_amdgcn_s_setprio(1);
                #pragma unroll
                for (int mi = 0; mi < 4; ++mi)
                    #pragma unroll
                    for (int ni = 0; ni < 4; ++ni)
                        acc[mi][ni] = __builtin_amdgcn_mfma_f32_16x16x32_bf16(
                            aY[mi], bY[ni], acc[mi][ni], 0, 0, 0);
                __builtin_amdgcn_s_setprio(0);
                LDA(aY, s2); LDB(bY, s2);          // refill Y for step s+2
            }
        }

        // per-tile epilogue: exp + in-lane partial sums (A pre-scaled by 2)
        #pragma unroll
        for (int mi = 0; mi < 4; ++mi)
            #pragma unroll
            for (int r = 0; r < 4; ++r) {
                float s = 0.f;
                #pragma unroll
                for (int ni = 0; ni < 4; ++ni)
                    s += __expf(acc[mi][ni][r]);
                partAcc[mi][r] += s;
            }
    }
    #undef LDA
    #undef LDB

    // block epilogue: reduce across the 16 column-lanes, one atomic set
    #pragma unroll
    for (int off = 1; off <= 8; off <<= 1)
        #pragma unroll
        for (int mi = 0; mi < 4; ++mi)
            #pragma unroll
            for (int r = 0; r < 4; ++r)
                partAcc[mi][r] += __shfl_xor(partAcc[mi][r], off);

    if ((l & 15) == 0) {
        const int rg = (l >> 4) * 4;     // C/D layout: row = (l>>4)*4 + reg
        #pragma unroll
        for (int mi = 0; mi < 4; ++mi)
            #pragma unroll
            for (int r = 0; r < 4; ++r)
                atomicAdd(&rowsum[rowBase + wr * 64 + mi * 16 + rg + r],
                          partAcc[mi][r]);
    }
}

// ---------------------------------------------------------------------------
// Kernel 3: loss = mean_b [ log(exp(pos_b) + rowsum_b) - pos_b ]
// ---------------------------------------------------------------------------
__global__ __launch_bounds__(1024) void finalize_kernel(
    const float* __restrict__ pos_logit, const float* __restrict__ rowsum,
    float* __restrict__ out, int B)
{
    __shared__ float red[1024];
    float acc = 0.f;
    for (int b = (int)threadIdx.x; b < B; b += 1024) {
        const float pl = pos_logit[b];
        acc += logf(expf(pl) + rowsum[b]) - pl;
    }
    red[threadIdx.x] = acc;
    __syncthreads();
    #pragma unroll
    for (int s = 512; s; s >>= 1) {
        if ((int)threadIdx.x < s) red[threadIdx.x] += red[threadIdx.x + s];
        __syncthreads();
    }
    if (threadIdx.x == 0) out[0] = red[0] / (float)B;
}

// ---------------------------------------------------------------------------
extern "C" void kernel_launch(void* const* d_in, const int* in_sizes, int n_in,
                              void* d_out, int out_size, void* d_ws, size_t ws_size,
                              hipStream_t stream)
{
    const float* ei = (const float*)d_in[0];
    const float* ej = (const float*)d_in[1];
    const float* ek = (const float*)d_in[2];
    const int B = in_sizes[0] / D_DIM;   // 8192

    unsigned short* zip = (unsigned short*)d_ws;            // 4 MB packed A
    unsigned short* zkp = zip + (size_t)B * D_DIM;          // 4 MB packed B
    float* rowsum       = (float*)(zkp + (size_t)B * D_DIM);
    float* pos_logit    = rowsum + B;

    prep_kernel<<<dim3(B / 16), dim3(256), 0, stream>>>(
        ei, ej, ek, zip, zkp, pos_logit, rowsum);

    dim3 grid(B / (NT * 256), B / BM);   // (8, 64) = 512 blocks x 512 thr
    sim_mfma_kernel<<<grid, dim3(512), 0, stream>>>(zip, zkp, rowsum);

    finalize_kernel<<<dim3(1), dim3(1024), 0, stream>>>(
        pos_logit, rowsum, (float*)d_out, B);
}

// Round 15
// 54.942 us; speedup vs baseline: 3.1108x; 1.0156x over previous
//
#include <hip/hip_runtime.h>
#include <hip/hip_fp8.h>
#include <cstdint>
#include <cstddef>

// ContrastiveLoss: B=8192, D=256 fp32 inputs.
// loss = mean_b [ log( exp(2*pos_b) + sum_c exp(2*z_i[b].z_k[c]) ) - 2*pos_b ]
// R14: MX-scaled fp8 MFMA (mfma_scale_f32_32x32x64_f8f6f4, 2x bf16 rate),
// LDS-free / barrier-free (R8-proven pattern). z_i/z_k normalized, quantized
// to OCP e4m3, packed in 32x64 fragment order (frag = 2048 B contiguous;
// lane l owns bytes [l*32,+32): row = l&31, k = (l>>5)*32 + e).
// Scale A = 2.0 (e8m0 0x80) folds 1/T into the HW dequant; scale B = 1.0.
// Per step/wave: 2 A-frag + 2 B-frag coalesced 32B/lane global reads (L2-hot,
// X/Y dbuf 2 steps ahead) + 4 MFMA. No LDS, no barriers.
// exp fused per col-tile; 32-lane shuffle-reduce + atomics once per block.
// BUGFIX vs R13: B col-group base is blockIdx.x*16 (512 cols / 32), was *32
// (OOB read -> 0xFF bytes = e4m3 NaN).

constexpr int   D_DIM = 256;
constexpr float INV_T = 2.0f;   // 1/T, T=0.5

constexpr int BM = 128;         // block rows
constexpr int NT = 4;           // col-tiles per block (each 128 cols)

typedef __attribute__((ext_vector_type(8)))  int   i32x8;
typedef __attribute__((ext_vector_type(16))) float f32x16;

// ---------------------------------------------------------------------------
// Kernel 1: per-16-row group: norms, pos_logit, rowsum init, PACKED e4m3 out.
// Thread t: row_local = t>>4, chunk c = t&15 (16 elems, k in [c*16,+16)).
// Pack target: frag f = (row>>5)*4 + (c>>2); lane = (row&31) + 32*((c>>1)&1);
// byte = f*2048 + lane*32 + (c&1)*16  -> one aligned 16-byte store.
// ---------------------------------------------------------------------------
__global__ __launch_bounds__(256) void prep_kernel(
    const float* __restrict__ ei, const float* __restrict__ ej,
    const float* __restrict__ ek,
    unsigned char* __restrict__ zip, unsigned char* __restrict__ zkp,
    float* __restrict__ pos_logit, float* __restrict__ rowsum)
{
    const int t  = (int)threadIdx.x;
    const int rl = t >> 4;              // row within group (0..15)
    const int c  = t & 15;              // 16-elem chunk (0..15)
    const int g  = (int)blockIdx.x;     // 16-row group
    const int row = g * 16 + rl;

    const float4* pi = (const float4*)(ei + (size_t)row * D_DIM + c * 16);
    const float4* pj = (const float4*)(ej + (size_t)row * D_DIM + c * 16);
    const float4* pk = (const float4*)(ek + (size_t)row * D_DIM + c * 16);
    float4 vi[4], vj[4], vk[4];
    #pragma unroll
    for (int q = 0; q < 4; ++q) { vi[q] = pi[q]; vj[q] = pj[q]; vk[q] = pk[q]; }

    float ssi = 0.f, ssj = 0.f, ssk = 0.f, dij = 0.f;
    #pragma unroll
    for (int q = 0; q < 4; ++q) {
        ssi += vi[q].x*vi[q].x + vi[q].y*vi[q].y + vi[q].z*vi[q].z + vi[q].w*vi[q].w;
        ssj += vj[q].x*vj[q].x + vj[q].y*vj[q].y + vj[q].z*vj[q].z + vj[q].w*vj[q].w;
        ssk += vk[q].x*vk[q].x + vk[q].y*vk[q].y + vk[q].z*vk[q].z + vk[q].w*vk[q].w;
        dij += vi[q].x*vj[q].x + vi[q].y*vj[q].y + vi[q].z*vj[q].z + vi[q].w*vj[q].w;
    }
    #pragma unroll
    for (int off = 1; off <= 8; off <<= 1) {    // reduce over the 16 c-lanes
        ssi += __shfl_xor(ssi, off);
        ssj += __shfl_xor(ssj, off);
        ssk += __shfl_xor(ssk, off);
        dij += __shfl_xor(dij, off);
    }
    const float ri = 1.0f / fmaxf(sqrtf(ssi), 1e-12f);
    const float rj = 1.0f / fmaxf(sqrtf(ssj), 1e-12f);
    const float rk = 1.0f / fmaxf(sqrtf(ssk), 1e-12f);

    union { unsigned char b[16]; uint4 v; } ui, uk;
    #pragma unroll
    for (int q = 0; q < 4; ++q) {
        const float* fi = &vi[q].x;
        const float* fk = &vk[q].x;
        #pragma unroll
        for (int e = 0; e < 4; ++e) {
            ui.b[q * 4 + e] = __hip_cvt_float_to_fp8(fi[e] * ri,
                                  __HIP_SATFINITE, __HIP_E4M3);
            uk.b[q * 4 + e] = __hip_cvt_float_to_fp8(fk[e] * rk,
                                  __HIP_SATFINITE, __HIP_E4M3);
        }
    }
    const int f    = (row >> 5) * 4 + (c >> 2);
    const int lane = (row & 31) + 32 * ((c >> 1) & 1);
    const size_t off = (size_t)f * 2048 + lane * 32 + (c & 1) * 16;
    *(uint4*)(zip + off) = ui.v;
    *(uint4*)(zkp + off) = uk.v;

    if (c == 0) {
        pos_logit[row] = dij * ri * rj * INV_T;
        rowsum[row]    = 0.0f;
    }
}

// ---------------------------------------------------------------------------
// Kernel 2: rows [by*128,+128) x cols [bx*512,+512) of exp-sum of
// 2*(z_i . z_k). 4 waves (2x2): wr=w>>1, wc=w&1; wave tile 64x64 =
// 2x2 frags of 32x32; K=64 per MFMA -> 4 K-steps per 128-col tile,
// NT=4 tiles -> 16 steps. A and B fragments read direct from global
// (32 B/lane coalesced, L2-resident), X/Y dbuf 2 steps ahead; no LDS,
// no barriers. Scale A = 2.0 (0x80 e8m0) applies 1/T; scale B = 1.0 (0x7F).
// ---------------------------------------------------------------------------
__global__ __launch_bounds__(256) void sim_mfma_kernel(
    const unsigned char* __restrict__ zip, const unsigned char* __restrict__ zkp,
    float* __restrict__ rowsum)
{
    const int t  = (int)threadIdx.x;
    const int w  = t >> 6;        // wave 0..3
    const int l  = t & 63;
    const int wr = w >> 1;        // row half (0..1)
    const int wc = w & 1;         // col half (0..1)
    const int rowBase = (int)blockIdx.y * BM;

    // ---- A frags: row-groups (by*4 + wr*2 + mi), kt 0..3.
    // frag byte base = group*4*2048; lane offset l*32.
    const unsigned char* Abase =
        zip + ((size_t)((int)blockIdx.y * 4 + wr * 2) * 4) * 2048 + (size_t)l * 32;
    #define LDA(dst, kt_) {                                                   \
        _Pragma("unroll")                                                     \
        for (int mi = 0; mi < 2; ++mi)                                        \
            dst[mi] = *(const i32x8*)(Abase                                   \
                + (size_t)((mi * 4) + (kt_)) * 2048);                         \
    }
    // ---- B frags: col-groups (bx*16 + wc*2 + nt*4 + ni), kt 0..3.
    const unsigned char* Bbase =
        zkp + ((size_t)((int)blockIdx.x * 16 + wc * 2) * 4) * 2048 + (size_t)l * 32;
    #define LDB(dst, s_) {                                                    \
        const int nt_ = (s_) >> 2, kt_ = (s_) & 3;                            \
        _Pragma("unroll")                                                     \
        for (int ni = 0; ni < 2; ++ni)                                        \
            dst[ni] = *(const i32x8*)(Bbase                                   \
                + (size_t)(((nt_ * 4 + ni) * 4 + kt_)) * 2048);               \
    }

    i32x8 aX[2], aY[2], bX[2], bY[2];
    LDA(aX, 0); LDB(bX, 0);           // step 0 -> X
    LDA(aY, 1); LDB(bY, 1);           // step 1 -> Y

    float partAcc[2][16] = {};

    for (int nt = 0; nt < NT; ++nt) {
        f32x16 acc[2][2] = {};

        #pragma unroll
        for (int k4 = 0; k4 < 4; ++k4) {
            const int s  = nt * 4 + k4;
            const int s2 = (s + 2 > NT * 4 - 1) ? (NT * 4 - 1) : (s + 2);
            const int kt2 = s2 & 3;               // kt of refill step

            if ((k4 & 1) == 0) {
                __builtin_amdgcn_s_setprio(1);
                #pragma unroll
                for (int mi = 0; mi < 2; ++mi)
                    #pragma unroll
                    for (int ni = 0; ni < 2; ++ni)
                        acc[mi][ni] = __builtin_amdgcn_mfma_scale_f32_32x32x64_f8f6f4(
                            aX[mi], bX[ni], acc[mi][ni],
                            0, 0,                 // cbsz=fp8(A), blgp=fp8(B)
                            0, 0x00000080,        // scale A = 2.0 (1/T)
                            0, 0x0000007F);       // scale B = 1.0
                __builtin_amdgcn_s_setprio(0);
                LDA(aX, kt2); LDB(bX, s2);        // refill X for step s+2
            } else {
                __builtin_amdgcn_s_setprio(1);
                #pragma unroll
                for (int mi = 0; mi < 2; ++mi)
                    #pragma unroll
                    for (int ni = 0; ni < 2; ++ni)
                        acc[mi][ni] = __builtin_amdgcn_mfma_scale_f32_32x32x64_f8f6f4(
                            aY[mi], bY[ni], acc[mi][ni],
                            0, 0, 0, 0x00000080, 0, 0x0000007F);
                __builtin_amdgcn_s_setprio(0);
                LDA(aY, kt2); LDB(bY, s2);        // refill Y for step s+2
            }
        }

        // per-tile epilogue: exp + in-lane partial sums
        #pragma unroll
        for (int mi = 0; mi < 2; ++mi)
            #pragma unroll
            for (int r = 0; r < 16; ++r)
                partAcc[mi][r] += __expf(acc[mi][0][r]) + __expf(acc[mi][1][r]);
    }
    #undef LDA
    #undef LDB

    // block epilogue: reduce across the 32 column-lanes (xor<32 stays in half)
    #pragma unroll
    for (int off = 1; off <= 16; off <<= 1)
        #pragma unroll
        for (int mi = 0; mi < 2; ++mi)
            #pragma unroll
            for (int r = 0; r < 16; ++r)
                partAcc[mi][r] += __shfl_xor(partAcc[mi][r], off);

    if ((l & 31) == 0) {
        const int hi = l >> 5;           // C/D: row = (r&3) + 8*(r>>2) + 4*hi
        #pragma unroll
        for (int mi = 0; mi < 2; ++mi)
            #pragma unroll
            for (int r = 0; r < 16; ++r) {
                const int rr = (r & 3) + 8 * (r >> 2) + 4 * hi;
                atomicAdd(&rowsum[rowBase + wr * 64 + mi * 32 + rr],
                          partAcc[mi][r]);
            }
    }
}

// ---------------------------------------------------------------------------
// Kernel 3: loss = mean_b [ log(exp(pos_b) + rowsum_b) - pos_b ]
// ---------------------------------------------------------------------------
__global__ __launch_bounds__(1024) void finalize_kernel(
    const float* __restrict__ pos_logit, const float* __restrict__ rowsum,
    float* __restrict__ out, int B)
{
    __shared__ float red[1024];
    float acc = 0.f;
    for (int b = (int)threadIdx.x; b < B; b += 1024) {
        const float pl = pos_logit[b];
        acc += logf(expf(pl) + rowsum[b]) - pl;
    }
    red[threadIdx.x] = acc;
    __syncthreads();
    #pragma unroll
    for (int s = 512; s; s >>= 1) {
        if ((int)threadIdx.x < s) red[threadIdx.x] += red[threadIdx.x + s];
        __syncthreads();
    }
    if (threadIdx.x == 0) out[0] = red[0] / (float)B;
}

// ---------------------------------------------------------------------------
extern "C" void kernel_launch(void* const* d_in, const int* in_sizes, int n_in,
                              void* d_out, int out_size, void* d_ws, size_t ws_size,
                              hipStream_t stream)
{
    const float* ei = (const float*)d_in[0];
    const float* ej = (const float*)d_in[1];
    const float* ek = (const float*)d_in[2];
    const int B = in_sizes[0] / D_DIM;   // 8192

    unsigned char* zip = (unsigned char*)d_ws;              // 2 MB packed fp8
    unsigned char* zkp = zip + (size_t)B * D_DIM;           // 2 MB packed fp8
    float* rowsum      = (float*)(zkp + (size_t)B * D_DIM);
    float* pos_logit   = rowsum + B;

    prep_kernel<<<dim3(B / 16), dim3(256), 0, stream>>>(
        ei, ej, ek, zip, zkp, pos_logit, rowsum);

    dim3 grid(B / (NT * 128), B / BM);   // (16, 64) = 1024 blocks
    sim_mfma_kernel<<<grid, dim3(256), 0, stream>>>(zip, zkp, rowsum);

    finalize_kernel<<<dim3(1), dim3(1024), 0, stream>>>(
        pos_logit, rowsum, (float*)d_out, B);
}

// Round 16
// 54.440 us; speedup vs baseline: 3.1395x; 1.0092x over previous
//
#include <hip/hip_runtime.h>
#include <cstdint>
#include <cstddef>

// ContrastiveLoss: B=8192, D=256 fp32 inputs.
// loss = mean_b [ log( exp(2*pos_b) + sum_c exp(2*z_i[b].z_k[c]) ) - 2*pos_b ]
// R15: fp8-MX MFMA (mfma_scale_f32_32x32x64_f8f6f4) with A panel resident in
// LDS (32 KB, linear gload_lds, contiguous conflict-free ds_read_b128 — the
// R10-verified pattern) and B streamed direct from global (R14-verified
// indexing), X/Y register dbuf 2 steps ahead. One barrier total.
// Scale A = 2.0 (e8m0 0x80) folds 1/T in HW dequant; scale B = 1.0 (0x7F).
// exp fused per col-tile; 32-lane shuffle-reduce + atomics once per block.

constexpr int   D_DIM = 256;
constexpr float INV_T = 2.0f;   // 1/T, T=0.5

constexpr int BM = 128;         // block rows
constexpr int NT = 4;           // col-tiles per block (each 128 cols)

typedef __attribute__((ext_vector_type(8)))  int   i32x8;
typedef __attribute__((ext_vector_type(16))) float f32x16;

__device__ __forceinline__ void gload_lds16(const void* g, void* l) {
    auto gp = reinterpret_cast<const __attribute__((address_space(1))) unsigned int*>(
        reinterpret_cast<uintptr_t>(g));
    auto lp = reinterpret_cast<__attribute__((address_space(3))) unsigned int*>(
        reinterpret_cast<uintptr_t>(l));
    __builtin_amdgcn_global_load_lds(gp, lp, 16, 0, 0);
}

// ---------------------------------------------------------------------------
// Kernel 1: per-16-row group: norms, pos_logit, rowsum init, PACKED e4m3 out.
// Thread t: row_local = t>>4, chunk c = t&15 (16 elems, k in [c*16,+16)).
// Pack (R14-verified): frag f = (row>>5)*4 + (c>>2);
// lane = (row&31) + 32*((c>>1)&1); byte = f*2048 + lane*32 + (c&1)*16.
// fp8 conversion via native v_cvt_pk_fp8_f32 (OCP e4m3 on gfx950).
// ---------------------------------------------------------------------------
__global__ __launch_bounds__(256) void prep_kernel(
    const float* __restrict__ ei, const float* __restrict__ ej,
    const float* __restrict__ ek,
    unsigned char* __restrict__ zip, unsigned char* __restrict__ zkp,
    float* __restrict__ pos_logit, float* __restrict__ rowsum)
{
    const int t  = (int)threadIdx.x;
    const int rl = t >> 4;              // row within group (0..15)
    const int c  = t & 15;              // 16-elem chunk (0..15)
    const int g  = (int)blockIdx.x;     // 16-row group
    const int row = g * 16 + rl;

    const float4* pi = (const float4*)(ei + (size_t)row * D_DIM + c * 16);
    const float4* pj = (const float4*)(ej + (size_t)row * D_DIM + c * 16);
    const float4* pk = (const float4*)(ek + (size_t)row * D_DIM + c * 16);
    float4 vi[4], vj[4], vk[4];
    #pragma unroll
    for (int q = 0; q < 4; ++q) { vi[q] = pi[q]; vj[q] = pj[q]; vk[q] = pk[q]; }

    float ssi = 0.f, ssj = 0.f, ssk = 0.f, dij = 0.f;
    #pragma unroll
    for (int q = 0; q < 4; ++q) {
        ssi += vi[q].x*vi[q].x + vi[q].y*vi[q].y + vi[q].z*vi[q].z + vi[q].w*vi[q].w;
        ssj += vj[q].x*vj[q].x + vj[q].y*vj[q].y + vj[q].z*vj[q].z + vj[q].w*vj[q].w;
        ssk += vk[q].x*vk[q].x + vk[q].y*vk[q].y + vk[q].z*vk[q].z + vk[q].w*vk[q].w;
        dij += vi[q].x*vj[q].x + vi[q].y*vj[q].y + vi[q].z*vj[q].z + vi[q].w*vj[q].w;
    }
    #pragma unroll
    for (int off = 1; off <= 8; off <<= 1) {    // reduce over the 16 c-lanes
        ssi += __shfl_xor(ssi, off);
        ssj += __shfl_xor(ssj, off);
        ssk += __shfl_xor(ssk, off);
        dij += __shfl_xor(dij, off);
    }
    const float ri = 1.0f / fmaxf(sqrtf(ssi), 1e-12f);
    const float rj = 1.0f / fmaxf(sqrtf(ssj), 1e-12f);
    const float rk = 1.0f / fmaxf(sqrtf(ssk), 1e-12f);

    // pack 16 normalized values each of z_i, z_k into 4 u32 (v_cvt_pk_fp8_f32)
    uint4 uiv, ukv;
    {
        unsigned int wi[4], wk[4];
        #pragma unroll
        for (int q = 0; q < 4; ++q) {
            const float* fi = &vi[q].x;
            const float* fk = &vk[q].x;
            int a = 0, b = 0;
            a = __builtin_amdgcn_cvt_pk_fp8_f32(fi[0] * ri, fi[1] * ri, a, false);
            a = __builtin_amdgcn_cvt_pk_fp8_f32(fi[2] * ri, fi[3] * ri, a, true);
            b = __builtin_amdgcn_cvt_pk_fp8_f32(fk[0] * rk, fk[1] * rk, b, false);
            b = __builtin_amdgcn_cvt_pk_fp8_f32(fk[2] * rk, fk[3] * rk, b, true);
            wi[q] = (unsigned int)a;
            wk[q] = (unsigned int)b;
        }
        uiv = make_uint4(wi[0], wi[1], wi[2], wi[3]);
        ukv = make_uint4(wk[0], wk[1], wk[2], wk[3]);
    }
    const int f    = (row >> 5) * 4 + (c >> 2);
    const int lane = (row & 31) + 32 * ((c >> 1) & 1);
    const size_t off = (size_t)f * 2048 + lane * 32 + (c & 1) * 16;
    *(uint4*)(zip + off) = uiv;
    *(uint4*)(zkp + off) = ukv;

    if (c == 0) {
        pos_logit[row] = dij * ri * rj * INV_T;
        rowsum[row]    = 0.0f;
    }
}

// ---------------------------------------------------------------------------
// Kernel 2: rows [by*128,+128) x cols [bx*512,+512) of exp-sum of
// 2*(z_i . z_k). 4 waves (2x2): wr=w>>1, wc=w&1; wave tile 64x64 =
// 2x2 frags of 32x32 K=64. A panel = 16 frags x 2048 B = 32 KB LDS
// (linear gload_lds; contiguous lane*32 ds_read -> conflict-free, R10-
// verified). B frags direct from global (32 B/lane coalesced, L2-resident),
// X/Y dbuf 2 steps ahead. One barrier total (after A staging).
// ---------------------------------------------------------------------------
__global__ __launch_bounds__(256) void sim_mfma_kernel(
    const unsigned char* __restrict__ zip, const unsigned char* __restrict__ zkp,
    float* __restrict__ rowsum)
{
    __shared__ __attribute__((aligned(16))) unsigned char Alds[16 * 2048];

    const int t  = (int)threadIdx.x;
    const int w  = t >> 6;        // wave 0..3
    const int l  = t & 63;
    const int wr = w >> 1;        // row half (0..1)
    const int wc = w & 1;         // col half (0..1)
    const int rowBase = (int)blockIdx.y * BM;

    // ---- stage A panel: global frags [by*16,+16) are contiguous 32 KB.
    // Wave w stages local frags [w*4,+4); 2 linear gload_lds16 per frag.
    const unsigned char* Ap = zip + (size_t)blockIdx.y * 16 * 2048;
    #pragma unroll
    for (int f = 0; f < 4; ++f) {
        const int fi = w * 4 + f;
        gload_lds16(Ap + (size_t)fi * 2048 +        (size_t)l * 16,
                    &Alds[fi * 2048]);
        gload_lds16(Ap + (size_t)fi * 2048 + 1024 + (size_t)l * 16,
                    &Alds[fi * 2048 + 1024]);
    }
    asm volatile("s_waitcnt vmcnt(0)" ::: "memory");
    __builtin_amdgcn_s_barrier();      // the ONLY barrier

    // ---- A frag read (LDS): local frag (mi,kt) = (wr*2+mi)*4 + kt;
    // lane l reads contiguous 32 B at +l*32 (conflict-free).
    #define LDA(dst, kt_) {                                                   \
        _Pragma("unroll")                                                     \
        for (int mi = 0; mi < 2; ++mi)                                        \
            dst[mi] = *(const i32x8*)&Alds[(((wr * 2 + mi) * 4 + (kt_)) * 2048) \
                                           + l * 32];                         \
    }
    // ---- B frags (global, R14-verified): col-group = bx*16 + wc*2 + nt*4 + ni.
    const unsigned char* Bbase =
        zkp + ((size_t)((int)blockIdx.x * 16 + wc * 2) * 4) * 2048 + (size_t)l * 32;
    #define LDB(dst, s_) {                                                    \
        const int nt_ = (s_) >> 2, kt_ = (s_) & 3;                            \
        _Pragma("unroll")                                                     \
        for (int ni = 0; ni < 2; ++ni)                                        \
            dst[ni] = *(const i32x8*)(Bbase                                   \
                + (size_t)(((nt_ * 4 + ni) * 4 + kt_)) * 2048);               \
    }

    i32x8 bX[2], bY[2];
    LDB(bX, 0);                        // step 0 -> X
    LDB(bY, 1);                        // step 1 -> Y

    float partAcc[2][16] = {};

    for (int nt = 0; nt < NT; ++nt) {
        f32x16 acc[2][2] = {};

        #pragma unroll
        for (int k4 = 0; k4 < 4; ++k4) {
            const int s  = nt * 4 + k4;
            const int s2 = (s + 2 > NT * 4 - 1) ? (NT * 4 - 1) : (s + 2);

            i32x8 a[2];
            LDA(a, k4);                          // kt compile-time

            if ((k4 & 1) == 0) {
                __builtin_amdgcn_s_setprio(1);
                #pragma unroll
                for (int mi = 0; mi < 2; ++mi)
                    #pragma unroll
                    for (int ni = 0; ni < 2; ++ni)
                        acc[mi][ni] = __builtin_amdgcn_mfma_scale_f32_32x32x64_f8f6f4(
                            a[mi], bX[ni], acc[mi][ni],
                            0, 0,                 // cbsz=fp8(A), blgp=fp8(B)
                            0, 0x00000080,        // scale A = 2.0 (1/T)
                            0, 0x0000007F);       // scale B = 1.0
                __builtin_amdgcn_s_setprio(0);
                LDB(bX, s2);                      // refill X for step s+2
            } else {
                __builtin_amdgcn_s_setprio(1);
                #pragma unroll
                for (int mi = 0; mi < 2; ++mi)
                    #pragma unroll
                    for (int ni = 0; ni < 2; ++ni)
                        acc[mi][ni] = __builtin_amdgcn_mfma_scale_f32_32x32x64_f8f6f4(
                            a[mi], bY[ni], acc[mi][ni],
                            0, 0, 0, 0x00000080, 0, 0x0000007F);
                __builtin_amdgcn_s_setprio(0);
                LDB(bY, s2);                      // refill Y for step s+2
            }
        }

        // per-tile epilogue: exp + in-lane partial sums
        #pragma unroll
        for (int mi = 0; mi < 2; ++mi)
            #pragma unroll
            for (int r = 0; r < 16; ++r)
                partAcc[mi][r] += __expf(acc[mi][0][r]) + __expf(acc[mi][1][r]);
    }
    #undef LDA
    #undef LDB

    // block epilogue: reduce across the 32 column-lanes (xor<32 stays in half)
    #pragma unroll
    for (int off = 1; off <= 16; off <<= 1)
        #pragma unroll
        for (int mi = 0; mi < 2; ++mi)
            #pragma unroll
            for (int r = 0; r < 16; ++r)
                partAcc[mi][r] += __shfl_xor(partAcc[mi][r], off);

    if ((l & 31) == 0) {
        const int hi = l >> 5;           // C/D: row = (r&3) + 8*(r>>2) + 4*hi
        #pragma unroll
        for (int mi = 0; mi < 2; ++mi)
            #pragma unroll
            for (int r = 0; r < 16; ++r) {
                const int rr = (r & 3) + 8 * (r >> 2) + 4 * hi;
                atomicAdd(&rowsum[rowBase + wr * 64 + mi * 32 + rr],
                          partAcc[mi][r]);
            }
    }
}

// ---------------------------------------------------------------------------
// Kernel 3: loss = mean_b [ log(exp(pos_b) + rowsum_b) - pos_b ]
// ---------------------------------------------------------------------------
__global__ __launch_bounds__(1024) void finalize_kernel(
    const float* __restrict__ pos_logit, const float* __restrict__ rowsum,
    float* __restrict__ out, int B)
{
    __shared__ float red[1024];
    float acc = 0.f;
    for (int b = (int)threadIdx.x; b < B; b += 1024) {
        const float pl = pos_logit[b];
        acc += logf(expf(pl) + rowsum[b]) - pl;
    }
    red[threadIdx.x] = acc;
    __syncthreads();
    #pragma unroll
    for (int s = 512; s; s >>= 1) {
        if ((int)threadIdx.x < s) red[threadIdx.x] += red[threadIdx.x + s];
        __syncthreads();
    }
    if (threadIdx.x == 0) out[0] = red[0] / (float)B;
}

// ---------------------------------------------------------------------------
extern "C" void kernel_launch(void* const* d_in, const int* in_sizes, int n_in,
                              void* d_out, int out_size, void* d_ws, size_t ws_size,
                              hipStream_t stream)
{
    const float* ei = (const float*)d_in[0];
    const float* ej = (const float*)d_in[1];
    const float* ek = (const float*)d_in[2];
    const int B = in_sizes[0] / D_DIM;   // 8192

    unsigned char* zip = (unsigned char*)d_ws;              // 2 MB packed fp8
    unsigned char* zkp = zip + (size_t)B * D_DIM;           // 2 MB packed fp8
    float* rowsum      = (float*)(zkp + (size_t)B * D_DIM);
    float* pos_logit   = rowsum + B;

    prep_kernel<<<dim3(B / 16), dim3(256), 0, stream>>>(
        ei, ej, ek, zip, zkp, pos_logit, rowsum);

    dim3 grid(B / (NT * 128), B / BM);   // (16, 64) = 1024 blocks
    sim_mfma_kernel<<<grid, dim3(256), 0, stream>>>(zip, zkp, rowsum);

    finalize_kernel<<<dim3(1), dim3(1024), 0, stream>>>(
        pos_logit, rowsum, (float*)d_out, B);
}